// Round 1
// baseline (702.304 us; speedup 1.0000x reference)
//
#include <hip/hip_runtime.h>
#include <math.h>

// Problem constants
#define TT 4096
#define DD 512
#define RR 32
#define CC 32
#define RC 1024
#define LL 2
#define CHUNK 64
#define NCHUNK 64
#define NEG_SLOPE 0.01f
#define LN_EPS 1e-5f

// ---------------------------------------------------------------------------
// h = x copy
__global__ __launch_bounds__(256) void copy4_kernel(const float4* __restrict__ src,
                                                    float4* __restrict__ dst, int n) {
    int i = blockIdx.x * 256 + threadIdx.x;
    if (i < n) dst[i] = src[i];
}

// ---------------------------------------------------------------------------
// tr = h @ Wt^T, ct = h @ Wc^T   (Wt/Wc: [32,512] row-major, K contiguous)
// one thread per output; j<32 -> tr, else ct
__global__ __launch_bounds__(256) void proj_kernel(const float* __restrict__ h,
                                                   const float* __restrict__ Wt,
                                                   const float* __restrict__ Wc,
                                                   float* __restrict__ trp,
                                                   float* __restrict__ ctp) {
    int tid = blockIdx.x * 256 + threadIdx.x;   // T*64 total
    int t = tid >> 6;
    int j = tid & 63;
    const float* w = (j < 32) ? (Wt + j * DD) : (Wc + (j - 32) * DD);
    const float4* hrow = (const float4*)(h + (size_t)t * DD);
    const float4* wrow = (const float4*)w;
    float acc = 0.f;
#pragma unroll 8
    for (int q = 0; q < DD / 4; ++q) {
        float4 hv = hrow[q], wv = wrow[q];
        acc += hv.x * wv.x + hv.y * wv.y + hv.z * wv.z + hv.w * wv.w;
    }
    if (j < 32) trp[t * RR + j] = acc;
    else        ctp[t * CC + (j - 32)] = acc;
}

// ---------------------------------------------------------------------------
// inv_denom[t] = 1 / (1e-8 + (sum_r |tr|) * (sum_c |ct|))
__global__ __launch_bounds__(256) void denom_kernel(const float* __restrict__ trp,
                                                    const float* __restrict__ ctp,
                                                    float* __restrict__ invd) {
    int t = blockIdx.x * 256 + threadIdx.x;
    if (t >= TT) return;
    float st = 0.f, sc = 0.f;
#pragma unroll
    for (int r = 0; r < RR; ++r) {
        st += fabsf(trp[t * RR + r]);
        sc += fabsf(ctp[t * CC + r]);
    }
    invd[t] = 1.f / (1e-8f + st * sc);
}

// ---------------------------------------------------------------------------
// Scan pass 1: per (chunk, r, c) compute affine transform (alpha, beta):
//   s_out = alpha * s_in + beta over the chunk, with segmentation resets.
__global__ __launch_bounds__(256) void scan_pass1(const float* __restrict__ trp,
                                                  const float* __restrict__ ctp,
                                                  const float* __restrict__ invd,
                                                  const int* __restrict__ start,
                                                  const float* __restrict__ a,
                                                  const float* __restrict__ b,
                                                  float4* __restrict__ ab4) {
    int tid = blockIdx.x * 256 + threadIdx.x;   // NCHUNK*RC = 65536
    int rc = tid & (RC - 1);
    int chunk = tid >> 10;
    int r = rc >> 5, c = rc & 31;
    float e = expf(-fabsf(a[r]));
    float gr = e * cosf(b[c]);
    float gi = e * sinf(b[c]);
    float alr = 1.f, ali = 0.f, ber = 0.f, bei = 0.f;
    int t0 = chunk * CHUNK;
    for (int j = 0; j < CHUNK; ++j) {
        int t = t0 + j;
        float pre = fabsf(trp[t * RR + r] * ctp[t * CC + c]) * invd[t];
        if (start[t]) {
            alr = 0.f; ali = 0.f; ber = pre; bei = 0.f;
        } else {
            float nbr = pre + gr * ber - gi * bei;
            float nbi =       gr * bei + gi * ber;
            float nar = gr * alr - gi * ali;
            float nai = gr * ali + gi * alr;
            ber = nbr; bei = nbi; alr = nar; ali = nai;
        }
    }
    ab4[chunk * RC + rc] = make_float4(alr, ali, ber, bei);
}

// ---------------------------------------------------------------------------
// Scan combine: sequential over the 64 chunk transforms per (r,c).
// Records the incoming state of every chunk.
__global__ __launch_bounds__(1024) void scan_combine(const float4* __restrict__ ab4,
                                                     const float* __restrict__ s0r,
                                                     const float* __restrict__ s0i,
                                                     float2* __restrict__ inc) {
    int rc = threadIdx.x;   // 1024
    float sr = s0r[rc], si = s0i[rc];
    for (int k = 0; k < NCHUNK; ++k) {
        inc[k * RC + rc] = make_float2(sr, si);
        float4 ab = ab4[k * RC + rc];
        float nsr = ab.z + ab.x * sr - ab.y * si;
        float nsi = ab.w + ab.x * si + ab.y * sr;
        sr = nsr; si = nsi;
    }
}

// ---------------------------------------------------------------------------
// Scan pass 2: rescan each chunk from its incoming state, emit scaled features:
//   scaled[t, rc]      = log1p(|s|) * im/|s|
//   scaled[t, 1024+rc] = log1p(|s|) * re/|s|
__global__ __launch_bounds__(256) void scan_pass2(const float* __restrict__ trp,
                                                  const float* __restrict__ ctp,
                                                  const float* __restrict__ invd,
                                                  const int* __restrict__ start,
                                                  const float* __restrict__ a,
                                                  const float* __restrict__ b,
                                                  const float2* __restrict__ inc,
                                                  float* __restrict__ scaled) {
    int tid = blockIdx.x * 256 + threadIdx.x;
    int rc = tid & (RC - 1);
    int chunk = tid >> 10;
    int r = rc >> 5, c = rc & 31;
    float e = expf(-fabsf(a[r]));
    float gr = e * cosf(b[c]);
    float gi = e * sinf(b[c]);
    float2 s = inc[chunk * RC + rc];
    float sr = s.x, si = s.y;
    int t0 = chunk * CHUNK;
    for (int j = 0; j < CHUNK; ++j) {
        int t = t0 + j;
        float pre = fabsf(trp[t * RR + r] * ctp[t * CC + c]) * invd[t];
        if (start[t]) {
            sr = pre; si = 0.f;
        } else {
            float nsr = pre + gr * sr - gi * si;
            float nsi =       gr * si + gi * sr;
            sr = nsr; si = nsi;
        }
        float m = sqrtf(sr * sr + si * si);
        float mag = log1pf(m);
        float f = (m > 0.f) ? (mag / m) : 0.f;
        scaled[(size_t)t * 2048 + rc]        = si * f;
        scaled[(size_t)t * 2048 + 1024 + rc] = sr * f;
    }
}

// ---------------------------------------------------------------------------
// C[M,N=512] = A[M,K] @ B[N,K]^T + bias   (fp32, 64x64 tile, 4x4 micro-tile)
template <int K>
__global__ __launch_bounds__(256) void gemm_bt(const float* __restrict__ A,
                                               const float* __restrict__ B,
                                               const float* __restrict__ bias,
                                               float* __restrict__ Cm) {
    __shared__ float As[16][68];
    __shared__ float Bs[16][68];
    int tid = threadIdx.x;
    int bm = blockIdx.y * 64;
    int bn = blockIdx.x * 64;
    int lr = tid >> 2;          // 0..63 row within tile
    int lk = (tid & 3) * 4;     // k offset 0,4,8,12
    int tx = tid & 15, ty = tid >> 4;
    float acc[4][4] = {};
    for (int k0 = 0; k0 < K; k0 += 16) {
        float4 av = *(const float4*)&A[(size_t)(bm + lr) * K + k0 + lk];
        float4 bv = *(const float4*)&B[(size_t)(bn + lr) * K + k0 + lk];
        As[lk + 0][lr] = av.x; As[lk + 1][lr] = av.y;
        As[lk + 2][lr] = av.z; As[lk + 3][lr] = av.w;
        Bs[lk + 0][lr] = bv.x; Bs[lk + 1][lr] = bv.y;
        Bs[lk + 2][lr] = bv.z; Bs[lk + 3][lr] = bv.w;
        __syncthreads();
#pragma unroll
        for (int kk = 0; kk < 16; ++kk) {
            float av4[4], bv4[4];
#pragma unroll
            for (int i = 0; i < 4; ++i) { av4[i] = As[kk][ty * 4 + i]; bv4[i] = Bs[kk][tx * 4 + i]; }
#pragma unroll
            for (int i = 0; i < 4; ++i)
#pragma unroll
                for (int j = 0; j < 4; ++j)
                    acc[i][j] += av4[i] * bv4[j];
        }
        __syncthreads();
    }
#pragma unroll
    for (int i = 0; i < 4; ++i)
#pragma unroll
        for (int j = 0; j < 4; ++j)
            Cm[(size_t)(bm + ty * 4 + i) * 512 + bn + tx * 4 + j] =
                acc[i][j] + bias[bn + tx * 4 + j];
}

// ---------------------------------------------------------------------------
// Per-row LayerNorm + LeakyReLU (+ optional residual-accumulate into h,
// + optional extra output write). block = 256 threads, one row of 512.
__global__ __launch_bounds__(256) void ln_lrelu_kernel(const float* __restrict__ y,
                                                       const float* __restrict__ g,
                                                       const float* __restrict__ be,
                                                       float* __restrict__ out,
                                                       float* __restrict__ hres,
                                                       float* __restrict__ fout) {
    int t = blockIdx.x;
    int tid = threadIdx.x;
    size_t base = (size_t)t * 512;
    float v0 = y[base + tid];
    float v1 = y[base + 256 + tid];
    float s = v0 + v1, ss = v0 * v0 + v1 * v1;
#pragma unroll
    for (int o = 32; o > 0; o >>= 1) {
        s  += __shfl_down(s, o);
        ss += __shfl_down(ss, o);
    }
    __shared__ float sh[8];
    __shared__ float mrs[2];
    int wid = tid >> 6, lane = tid & 63;
    if (lane == 0) { sh[wid] = s; sh[4 + wid] = ss; }
    __syncthreads();
    if (tid == 0) {
        float S = sh[0] + sh[1] + sh[2] + sh[3];
        float SS = sh[4] + sh[5] + sh[6] + sh[7];
        float m = S * (1.f / 512.f);
        float var = SS * (1.f / 512.f) - m * m;
        mrs[0] = m;
        mrs[1] = rsqrtf(var + LN_EPS);
    }
    __syncthreads();
    float m = mrs[0], rs = mrs[1];
    float z0 = g[tid] * (v0 - m) * rs + be[tid];
    float z1 = g[256 + tid] * (v1 - m) * rs + be[256 + tid];
    z0 = (z0 > 0.f) ? z0 : NEG_SLOPE * z0;
    z1 = (z1 > 0.f) ? z1 : NEG_SLOPE * z1;
    if (out)  { out[base + tid] = z0;  out[base + 256 + tid] = z1; }
    if (hres) { hres[base + tid] += z0; hres[base + 256 + tid] += z1; }
    if (fout) { fout[base + tid] = z0; fout[base + 256 + tid] = z1; }
}

// ---------------------------------------------------------------------------
extern "C" void kernel_launch(void* const* d_in, const int* in_sizes, int n_in,
                              void* d_out, int out_size, void* d_ws, size_t ws_size,
                              hipStream_t stream) {
    const float* x     = (const float*)d_in[0];
    const int*   start = (const int*)d_in[1];
    // d_in[2] = next_done (unused)
    const float* s0r = (const float*)d_in[3];
    const float* s0i = (const float*)d_in[4];
    const float* Wt  = (const float*)d_in[5];
    const float* Wc  = (const float*)d_in[6];
    const float* a   = (const float*)d_in[7];
    const float* b   = (const float*)d_in[8];
    const float* W0  = (const float*)d_in[9];
    const float* b0  = (const float*)d_in[10];
    const float* g0  = (const float*)d_in[11];
    const float* be0 = (const float*)d_in[12];
    const float* W1  = (const float*)d_in[13];
    const float* b1  = (const float*)d_in[14];
    const float* g1  = (const float*)d_in[15];
    const float* be1 = (const float*)d_in[16];
    float* out = (float*)d_out;
    float* ws  = (float*)d_ws;

    // workspace layout (float offsets)
    float* h      = ws;                       // 2097152
    float* trp    = ws + 2097152;             // 131072
    float* ctp    = trp + 131072;             // 131072
    float* invd   = ctp + 131072;             // 4096
    float4* ab4   = (float4*)(invd + 4096);   // 65536 float4 = 262144 floats
    float2* inc   = (float2*)(invd + 4096 + 262144);   // 131072 floats
    float* scaled = invd + 4096 + 262144 + 131072;     // 8388608
    float* ybuf   = scaled + 8388608;         // 2097152
    float* zbuf   = ybuf + 2097152;           // 2097152
    // total: 15,339,520 floats = ~61.4 MB

    // h = x
    copy4_kernel<<<(TT * DD / 4 + 255) / 256, 256, 0, stream>>>(
        (const float4*)x, (float4*)h, TT * DD / 4);

    for (int i = 0; i < LL; ++i) {
        proj_kernel<<<TT * 64 / 256, 256, 0, stream>>>(
            h, Wt + (size_t)i * RR * DD, Wc + (size_t)i * RR * DD, trp, ctp);
        denom_kernel<<<TT / 256, 256, 0, stream>>>(trp, ctp, invd);
        scan_pass1<<<NCHUNK * RC / 256, 256, 0, stream>>>(
            trp, ctp, invd, start, a + i * RR, b + i * CC, ab4);
        scan_combine<<<1, 1024, 0, stream>>>(ab4, s0r + i * RC, s0i + i * RC, inc);
        scan_pass2<<<NCHUNK * RC / 256, 256, 0, stream>>>(
            trp, ctp, invd, start, a + i * RR, b + i * CC, inc, scaled);
        gemm_bt<2048><<<dim3(8, 64), 256, 0, stream>>>(
            scaled, W0 + (size_t)i * DD * 2048, b0 + i * DD, ybuf);
        ln_lrelu_kernel<<<TT, 256, 0, stream>>>(
            ybuf, g0 + i * DD, be0 + i * DD, zbuf, nullptr, nullptr);
        gemm_bt<512><<<dim3(8, 64), 256, 0, stream>>>(
            zbuf, W1 + (size_t)i * DD * DD, b1 + i * DD, ybuf);
        ln_lrelu_kernel<<<TT, 256, 0, stream>>>(
            ybuf, g1 + i * DD, be1 + i * DD, nullptr, h,
            (i == LL - 1) ? out : nullptr);
    }
}

// Round 2
// 418.487 us; speedup vs baseline: 1.6782x; 1.6782x over previous
//
#include <hip/hip_runtime.h>
#include <math.h>

// Problem constants
#define TT 4096
#define DD 512
#define RR 32
#define CC 32
#define RC 1024
#define LL 2
#define CHUNK 64
#define NCHUNK 64
#define NEG_SLOPE 0.01f
#define LN_EPS 1e-5f

typedef __attribute__((ext_vector_type(8))) __bf16 bf16x8;
typedef __attribute__((ext_vector_type(4))) float f32x4;

__device__ __forceinline__ unsigned short f2bf(float f) {
    unsigned int u = __builtin_bit_cast(unsigned int, f);
    u += 0x7fffu + ((u >> 16) & 1u);   // round-to-nearest-even
    return (unsigned short)(u >> 16);
}

// ---------------------------------------------------------------------------
// h = x copy
__global__ __launch_bounds__(256) void copy4_kernel(const float4* __restrict__ src,
                                                    float4* __restrict__ dst, int n) {
    int i = blockIdx.x * 256 + threadIdx.x;
    if (i < n) dst[i] = src[i];
}

// ---------------------------------------------------------------------------
// f32 -> bf16 bits (4 elems/thread)
__global__ __launch_bounds__(256) void f32_to_bf16_kernel(const float4* __restrict__ src,
                                                          ushort4* __restrict__ dst, int n4) {
    int i = blockIdx.x * 256 + threadIdx.x;
    if (i >= n4) return;
    float4 v = src[i];
    ushort4 o;
    o.x = f2bf(v.x); o.y = f2bf(v.y); o.z = f2bf(v.z); o.w = f2bf(v.w);
    dst[i] = o;
}

// ---------------------------------------------------------------------------
// tr = h @ Wt^T, ct = h @ Wc^T
__global__ __launch_bounds__(256) void proj_kernel(const float* __restrict__ h,
                                                   const float* __restrict__ Wt,
                                                   const float* __restrict__ Wc,
                                                   float* __restrict__ trp,
                                                   float* __restrict__ ctp) {
    int tid = blockIdx.x * 256 + threadIdx.x;   // T*64 total
    int t = tid >> 6;
    int j = tid & 63;
    const float* w = (j < 32) ? (Wt + j * DD) : (Wc + (j - 32) * DD);
    const float4* hrow = (const float4*)(h + (size_t)t * DD);
    const float4* wrow = (const float4*)w;
    float acc = 0.f;
#pragma unroll 8
    for (int q = 0; q < DD / 4; ++q) {
        float4 hv = hrow[q], wv = wrow[q];
        acc += hv.x * wv.x + hv.y * wv.y + hv.z * wv.z + hv.w * wv.w;
    }
    if (j < 32) trp[t * RR + j] = acc;
    else        ctp[t * CC + (j - 32)] = acc;
}

// ---------------------------------------------------------------------------
__global__ __launch_bounds__(256) void denom_kernel(const float* __restrict__ trp,
                                                    const float* __restrict__ ctp,
                                                    float* __restrict__ invd) {
    int t = blockIdx.x * 256 + threadIdx.x;
    if (t >= TT) return;
    float st = 0.f, sc = 0.f;
#pragma unroll
    for (int r = 0; r < RR; ++r) {
        st += fabsf(trp[t * RR + r]);
        sc += fabsf(ctp[t * CC + r]);
    }
    invd[t] = 1.f / (1e-8f + st * sc);
}

// ---------------------------------------------------------------------------
// Scan pass 1: per (chunk, r, c) affine transform (alpha, beta) with resets.
__global__ __launch_bounds__(256) void scan_pass1(const float* __restrict__ trp,
                                                  const float* __restrict__ ctp,
                                                  const float* __restrict__ invd,
                                                  const int* __restrict__ start,
                                                  const float* __restrict__ a,
                                                  const float* __restrict__ b,
                                                  float4* __restrict__ ab4) {
    int tid = blockIdx.x * 256 + threadIdx.x;   // NCHUNK*RC = 65536
    int rc = tid & (RC - 1);
    int chunk = tid >> 10;
    int r = rc >> 5, c = rc & 31;
    float e = expf(-fabsf(a[r]));
    float gr = e * cosf(b[c]);
    float gi = e * sinf(b[c]);
    float alr = 1.f, ali = 0.f, ber = 0.f, bei = 0.f;
    int t0 = chunk * CHUNK;
    for (int j = 0; j < CHUNK; ++j) {
        int t = t0 + j;
        float pre = fabsf(trp[t * RR + r] * ctp[t * CC + c]) * invd[t];
        if (start[t]) {
            alr = 0.f; ali = 0.f; ber = pre; bei = 0.f;
        } else {
            float nbr = pre + gr * ber - gi * bei;
            float nbi =       gr * bei + gi * ber;
            float nar = gr * alr - gi * ali;
            float nai = gr * ali + gi * alr;
            ber = nbr; bei = nbi; alr = nar; ali = nai;
        }
    }
    ab4[chunk * RC + rc] = make_float4(alr, ali, ber, bei);
}

// ---------------------------------------------------------------------------
__global__ __launch_bounds__(1024) void scan_combine(const float4* __restrict__ ab4,
                                                     const float* __restrict__ s0r,
                                                     const float* __restrict__ s0i,
                                                     float2* __restrict__ inc) {
    int rc = threadIdx.x;   // 1024
    float sr = s0r[rc], si = s0i[rc];
    for (int k = 0; k < NCHUNK; ++k) {
        inc[k * RC + rc] = make_float2(sr, si);
        float4 ab = ab4[k * RC + rc];
        float nsr = ab.z + ab.x * sr - ab.y * si;
        float nsi = ab.w + ab.x * si + ab.y * sr;
        sr = nsr; si = nsi;
    }
}

// ---------------------------------------------------------------------------
// Scan pass 2: rescan chunk, emit scaled features in bf16.
__global__ __launch_bounds__(256) void scan_pass2(const float* __restrict__ trp,
                                                  const float* __restrict__ ctp,
                                                  const float* __restrict__ invd,
                                                  const int* __restrict__ start,
                                                  const float* __restrict__ a,
                                                  const float* __restrict__ b,
                                                  const float2* __restrict__ inc,
                                                  unsigned short* __restrict__ scaled) {
    int tid = blockIdx.x * 256 + threadIdx.x;
    int rc = tid & (RC - 1);
    int chunk = tid >> 10;
    int r = rc >> 5, c = rc & 31;
    float e = expf(-fabsf(a[r]));
    float gr = e * cosf(b[c]);
    float gi = e * sinf(b[c]);
    float2 s = inc[chunk * RC + rc];
    float sr = s.x, si = s.y;
    int t0 = chunk * CHUNK;
    for (int j = 0; j < CHUNK; ++j) {
        int t = t0 + j;
        float pre = fabsf(trp[t * RR + r] * ctp[t * CC + c]) * invd[t];
        if (start[t]) {
            sr = pre; si = 0.f;
        } else {
            float nsr = pre + gr * sr - gi * si;
            float nsi =       gr * si + gi * sr;
            sr = nsr; si = nsi;
        }
        float m = sqrtf(sr * sr + si * si);
        float mag = log1pf(m);
        float f = (m > 0.f) ? (mag / m) : 0.f;
        scaled[(size_t)t * 2048 + rc]        = f2bf(si * f);
        scaled[(size_t)t * 2048 + 1024 + rc] = f2bf(sr * f);
    }
}

// ---------------------------------------------------------------------------
// C[4096,512] = A[M,K]bf16 @ B[512,K]bf16^T + bias, fp32 out.
// Tile 128x64, BK=32, 4 waves (each 64x32 = 4x2 frags of 16x16x32 MFMA).
// Reg-staged LDS with XOR slot swizzle (slot ^= (row>>1)&3) on write AND read.
template <int K>
__global__ __launch_bounds__(256) void gemm_bt_mfma(const unsigned short* __restrict__ A,
                                                    const unsigned short* __restrict__ B,
                                                    const float* __restrict__ bias,
                                                    float* __restrict__ Cm) {
    __shared__ unsigned short As[128 * 32];
    __shared__ unsigned short Bs[64 * 32];
    const int tid = threadIdx.x;
    const int w = tid >> 6, lane = tid & 63;
    const int bm = blockIdx.y * 128, bn = blockIdx.x * 64;
    const int wr = w >> 1, wc = w & 1;            // wave tile: rows wr*64, cols wc*32
    const int lr = lane >> 2;                     // 0..15 staging row in group
    const int sl = lane & 3;                      // 16B slot
    const int swz_st = sl ^ ((lr >> 1) & 3);      // LDS write slot
    // staging source rows
    const size_t a_row0 = (size_t)(bm + w * 16 + lr);
    const size_t a_row1 = (size_t)(bm + 64 + w * 16 + lr);
    const size_t b_row  = (size_t)(bn + w * 16 + lr);
    const unsigned short* gA0 = A + a_row0 * K + sl * 8;
    const unsigned short* gA1 = A + a_row1 * K + sl * 8;
    const unsigned short* gB  = B + b_row  * K + sl * 8;
    // LDS write element indices (row*32 + slot*8)
    const int wA0 = (w * 16 + lr) * 32 + swz_st * 8;
    const int wA1 = (64 + w * 16 + lr) * 32 + swz_st * 8;
    const int wB  = (w * 16 + lr) * 32 + swz_st * 8;
    // read addressing
    const int fr = lane & 15;
    const int kslot = (lane >> 4) ^ ((fr >> 1) & 3);
    f32x4 acc[4][2] = {};

    uint4 va0 = *(const uint4*)gA0;
    uint4 va1 = *(const uint4*)gA1;
    uint4 vb  = *(const uint4*)gB;
    for (int k0 = 0; k0 < K; k0 += 32) {
        __syncthreads();   // previous tile's reads done
        *(uint4*)&As[wA0] = va0;
        *(uint4*)&As[wA1] = va1;
        *(uint4*)&Bs[wB]  = vb;
        __syncthreads();   // stores visible
        if (k0 + 32 < K) { // prefetch next tile (overlaps MFMA below)
            va0 = *(const uint4*)(gA0 + k0 + 32);
            va1 = *(const uint4*)(gA1 + k0 + 32);
            vb  = *(const uint4*)(gB  + k0 + 32);
        }
        bf16x8 af[4], bfr[2];
#pragma unroll
        for (int mi = 0; mi < 4; ++mi) {
            int row = wr * 64 + mi * 16 + fr;
            af[mi] = *(const bf16x8*)&As[row * 32 + kslot * 8];
        }
#pragma unroll
        for (int ni = 0; ni < 2; ++ni) {
            int row = wc * 32 + ni * 16 + fr;
            bfr[ni] = *(const bf16x8*)&Bs[row * 32 + kslot * 8];
        }
#pragma unroll
        for (int mi = 0; mi < 4; ++mi)
#pragma unroll
            for (int ni = 0; ni < 2; ++ni)
                acc[mi][ni] = __builtin_amdgcn_mfma_f32_16x16x32_bf16(
                    af[mi], bfr[ni], acc[mi][ni], 0, 0, 0);
    }
    // epilogue: C/D layout col=lane&15, row=(lane>>4)*4+reg  [m89]
    const int ccol0 = bn + wc * 32 + fr;
    const int crow0 = bm + wr * 64 + (lane >> 4) * 4;
#pragma unroll
    for (int ni = 0; ni < 2; ++ni) {
        int col = ccol0 + ni * 16;
        float bv = bias[col];
#pragma unroll
        for (int mi = 0; mi < 4; ++mi)
#pragma unroll
            for (int q = 0; q < 4; ++q)
                Cm[(size_t)(crow0 + mi * 16 + q) * 512 + col] = acc[mi][ni][q] + bv;
    }
}

// ---------------------------------------------------------------------------
// Per-row LayerNorm + LeakyReLU. Optional bf16 z out, f32 residual-add, f32 out.
__global__ __launch_bounds__(256) void ln_lrelu_kernel(const float* __restrict__ y,
                                                       const float* __restrict__ g,
                                                       const float* __restrict__ be,
                                                       unsigned short* __restrict__ zb,
                                                       float* __restrict__ hres,
                                                       float* __restrict__ fout) {
    int t = blockIdx.x;
    int tid = threadIdx.x;
    size_t base = (size_t)t * 512;
    float v0 = y[base + tid];
    float v1 = y[base + 256 + tid];
    float s = v0 + v1, ss = v0 * v0 + v1 * v1;
#pragma unroll
    for (int o = 32; o > 0; o >>= 1) {
        s  += __shfl_down(s, o);
        ss += __shfl_down(ss, o);
    }
    __shared__ float sh[8];
    __shared__ float mrs[2];
    int wid = tid >> 6, lane = tid & 63;
    if (lane == 0) { sh[wid] = s; sh[4 + wid] = ss; }
    __syncthreads();
    if (tid == 0) {
        float S = sh[0] + sh[1] + sh[2] + sh[3];
        float SS = sh[4] + sh[5] + sh[6] + sh[7];
        float m = S * (1.f / 512.f);
        float var = SS * (1.f / 512.f) - m * m;
        mrs[0] = m;
        mrs[1] = rsqrtf(var + LN_EPS);
    }
    __syncthreads();
    float m = mrs[0], rs = mrs[1];
    float z0 = g[tid] * (v0 - m) * rs + be[tid];
    float z1 = g[256 + tid] * (v1 - m) * rs + be[256 + tid];
    z0 = (z0 > 0.f) ? z0 : NEG_SLOPE * z0;
    z1 = (z1 > 0.f) ? z1 : NEG_SLOPE * z1;
    if (zb)   { zb[base + tid] = f2bf(z0); zb[base + 256 + tid] = f2bf(z1); }
    if (hres) { hres[base + tid] += z0; hres[base + 256 + tid] += z1; }
    if (fout) { fout[base + tid] = z0; fout[base + 256 + tid] = z1; }
}

// ---------------------------------------------------------------------------
extern "C" void kernel_launch(void* const* d_in, const int* in_sizes, int n_in,
                              void* d_out, int out_size, void* d_ws, size_t ws_size,
                              hipStream_t stream) {
    const float* x     = (const float*)d_in[0];
    const int*   start = (const int*)d_in[1];
    const float* s0r = (const float*)d_in[3];
    const float* s0i = (const float*)d_in[4];
    const float* Wt  = (const float*)d_in[5];
    const float* Wc  = (const float*)d_in[6];
    const float* a   = (const float*)d_in[7];
    const float* b   = (const float*)d_in[8];
    const float* W0  = (const float*)d_in[9];
    const float* b0  = (const float*)d_in[10];
    const float* g0  = (const float*)d_in[11];
    const float* be0 = (const float*)d_in[12];
    const float* W1  = (const float*)d_in[13];
    const float* b1  = (const float*)d_in[14];
    const float* g1  = (const float*)d_in[15];
    const float* be1 = (const float*)d_in[16];
    float* out = (float*)d_out;
    float* ws  = (float*)d_ws;

    // workspace layout (float-unit offsets, all 16B aligned)
    float* h      = ws;                                   // 2,097,152 f
    float* trp    = h + 2097152;                          //   131,072 f
    float* ctp    = trp + 131072;                         //   131,072 f
    float* invd   = ctp + 131072;                         //     4,096 f
    float4* ab4   = (float4*)(invd + 4096);               //   262,144 f
    float2* inc   = (float2*)(invd + 4096 + 262144);      //   131,072 f
    unsigned short* scaled = (unsigned short*)(invd + 4096 + 262144 + 131072); // 8,388,608 bf16 = 4,194,304 f
    float* ybuf   = invd + 4096 + 262144 + 131072 + 4194304;  // 2,097,152 f
    unsigned short* zbuf_bf = (unsigned short*)(ybuf + 2097152);   // 2,097,152 bf16 = 1,048,576 f
    unsigned short* W0bf = (unsigned short*)(ybuf + 2097152 + 1048576);  // 2,097,152 bf16 = 1,048,576 f
    unsigned short* W1bf = (unsigned short*)(ybuf + 2097152 + 1048576 + 1048576); // 524,288 bf16 = 262,144 f
    // total ≈ 11.4M floats ≈ 45.8 MB

    // h = x ; weight conversions (both layers at once)
    copy4_kernel<<<2048, 256, 0, stream>>>((const float4*)x, (float4*)h, TT * DD / 4);
    f32_to_bf16_kernel<<<2048, 256, 0, stream>>>((const float4*)W0, (ushort4*)W0bf,
                                                 LL * DD * 2048 / 4);
    f32_to_bf16_kernel<<<512, 256, 0, stream>>>((const float4*)W1, (ushort4*)W1bf,
                                                LL * DD * DD / 4);

    for (int i = 0; i < LL; ++i) {
        proj_kernel<<<TT * 64 / 256, 256, 0, stream>>>(
            h, Wt + (size_t)i * RR * DD, Wc + (size_t)i * RR * DD, trp, ctp);
        denom_kernel<<<TT / 256, 256, 0, stream>>>(trp, ctp, invd);
        scan_pass1<<<NCHUNK * RC / 256, 256, 0, stream>>>(
            trp, ctp, invd, start, a + i * RR, b + i * CC, ab4);
        scan_combine<<<1, 1024, 0, stream>>>(ab4, s0r + i * RC, s0i + i * RC, inc);
        scan_pass2<<<NCHUNK * RC / 256, 256, 0, stream>>>(
            trp, ctp, invd, start, a + i * RR, b + i * CC, inc, scaled);
        gemm_bt_mfma<2048><<<dim3(8, 32), 256, 0, stream>>>(
            scaled, W0bf + (size_t)i * DD * 2048, b0 + i * DD, ybuf);
        ln_lrelu_kernel<<<TT, 256, 0, stream>>>(
            ybuf, g0 + i * DD, be0 + i * DD, zbuf_bf, nullptr, nullptr);
        gemm_bt_mfma<512><<<dim3(8, 32), 256, 0, stream>>>(
            zbuf_bf, W1bf + (size_t)i * DD * DD, b1 + i * DD, ybuf);
        ln_lrelu_kernel<<<TT, 256, 0, stream>>>(
            ybuf, g1 + i * DD, be1 + i * DD, nullptr,
            (i < LL - 1) ? h : nullptr,
            (i == LL - 1) ? out : nullptr);
    }
}

// Round 3
// 230.942 us; speedup vs baseline: 3.0410x; 1.8121x over previous
//
#include <hip/hip_runtime.h>
#include <math.h>

// Problem constants
#define TT 4096
#define DD 512
#define RR 32
#define CC 32
#define RC 1024
#define LL 2
#define CHUNK 32
#define NCHUNK 128
#define NEG_SLOPE 0.01f
#define LN_EPS 1e-5f

typedef __attribute__((ext_vector_type(8))) __bf16 bf16x8;
typedef __attribute__((ext_vector_type(4))) float f32x4;

__device__ __forceinline__ unsigned short f2bf(float f) {
    unsigned int u = __builtin_bit_cast(unsigned int, f);
    u += 0x7fffu + ((u >> 16) & 1u);   // round-to-nearest-even
    return (unsigned short)(u >> 16);
}

// ---------------------------------------------------------------------------
// f32 -> bf16 bits (4 elems/thread)
__global__ __launch_bounds__(256) void f32_to_bf16_kernel(const float4* __restrict__ src,
                                                          ushort4* __restrict__ dst, int n4) {
    int i = blockIdx.x * 256 + threadIdx.x;
    if (i >= n4) return;
    float4 v = src[i];
    ushort4 o;
    o.x = f2bf(v.x); o.y = f2bf(v.y); o.z = f2bf(v.z); o.w = f2bf(v.w);
    dst[i] = o;
}

// ---------------------------------------------------------------------------
// Pack Wt[L,32,512] and Wc[L,32,512] into Wtc[L,64,512] bf16 (rows 0..31 = Wt)
__global__ __launch_bounds__(256) void pack_wtc_kernel(const float* __restrict__ Wt,
                                                       const float* __restrict__ Wc,
                                                       ushort4* __restrict__ Wtc) {
    int i = blockIdx.x * 256 + threadIdx.x;      // vec4 index, L*64*512/4 total
    int e = i * 4;
    int l = e >> 15;          // / (64*512)
    int r = (e >> 9) & 63;
    int k = e & 511;
    const float4 v = (r < 32)
        ? *(const float4*)&Wt[((size_t)l * 32 + r) * 512 + k]
        : *(const float4*)&Wc[((size_t)l * 32 + (r - 32)) * 512 + k];
    ushort4 o;
    o.x = f2bf(v.x); o.y = f2bf(v.y); o.z = f2bf(v.z); o.w = f2bf(v.w);
    Wtc[i] = o;
}

// ---------------------------------------------------------------------------
// invd[t] = 1 / (1e-8 + (sum_r |tr|)(sum_c |ct|)), tc layout [T,64] (tr||ct)
__global__ __launch_bounds__(256) void denom_kernel(const float* __restrict__ tc,
                                                    float* __restrict__ invd) {
    int t = blockIdx.x * 256 + threadIdx.x;
    if (t >= TT) return;
    const float4* p = (const float4*)(tc + (size_t)t * 64);
    float st = 0.f, sc = 0.f;
#pragma unroll
    for (int q = 0; q < 8; ++q) {
        float4 v = p[q];
        st += fabsf(v.x) + fabsf(v.y) + fabsf(v.z) + fabsf(v.w);
    }
#pragma unroll
    for (int q = 8; q < 16; ++q) {
        float4 v = p[q];
        sc += fabsf(v.x) + fabsf(v.y) + fabsf(v.z) + fabsf(v.w);
    }
    invd[t] = 1.f / (1e-8f + st * sc);
}

// ---------------------------------------------------------------------------
// Scan pass 1: per (chunk, r, c) affine transform (alpha, beta) with resets.
__global__ __launch_bounds__(256) void scan_pass1(const float* __restrict__ tc,
                                                  const float* __restrict__ invd,
                                                  const int* __restrict__ start,
                                                  const float* __restrict__ a,
                                                  const float* __restrict__ b,
                                                  float4* __restrict__ ab4) {
    int tid = blockIdx.x * 256 + threadIdx.x;   // NCHUNK*RC = 131072
    int rc = tid & (RC - 1);
    int chunk = tid >> 10;
    int r = rc >> 5, c = rc & 31;
    float e = expf(-fabsf(a[r]));
    float gr = e * cosf(b[c]);
    float gi = e * sinf(b[c]);
    float alr = 1.f, ali = 0.f, ber = 0.f, bei = 0.f;
    int t0 = chunk * CHUNK;
    for (int j = 0; j < CHUNK; ++j) {
        int t = t0 + j;
        float pre = fabsf(tc[t * 64 + r] * tc[t * 64 + 32 + c]) * invd[t];
        if (start[t]) {
            alr = 0.f; ali = 0.f; ber = pre; bei = 0.f;
        } else {
            float nbr = pre + gr * ber - gi * bei;
            float nbi =       gr * bei + gi * ber;
            float nar = gr * alr - gi * ali;
            float nai = gr * ali + gi * alr;
            ber = nbr; bei = nbi; alr = nar; ali = nai;
        }
    }
    ab4[chunk * RC + rc] = make_float4(alr, ali, ber, bei);
}

// ---------------------------------------------------------------------------
// Combine: sequential scan over NCHUNK chunk transforms per (r,c), with
// 8-deep batched prefetch of the (scan-independent) ab4 loads.
__global__ __launch_bounds__(256) void scan_combine(const float4* __restrict__ ab4,
                                                    const float* __restrict__ s0r,
                                                    const float* __restrict__ s0i,
                                                    float2* __restrict__ inc) {
    int rc = blockIdx.x * 256 + threadIdx.x;   // 1024 total
    float sr = s0r[rc], si = s0i[rc];
    for (int kb = 0; kb < NCHUNK; kb += 8) {
        float4 buf[8];
#pragma unroll
        for (int u = 0; u < 8; ++u) buf[u] = ab4[(kb + u) * RC + rc];
#pragma unroll
        for (int u = 0; u < 8; ++u) {
            inc[(kb + u) * RC + rc] = make_float2(sr, si);
            float nsr = buf[u].z + buf[u].x * sr - buf[u].y * si;
            float nsi = buf[u].w + buf[u].x * si + buf[u].y * sr;
            sr = nsr; si = nsi;
        }
    }
}

// ---------------------------------------------------------------------------
// Scan pass 2: rescan chunk from incoming state, emit scaled features (bf16).
__global__ __launch_bounds__(256) void scan_pass2(const float* __restrict__ tc,
                                                  const float* __restrict__ invd,
                                                  const int* __restrict__ start,
                                                  const float* __restrict__ a,
                                                  const float* __restrict__ b,
                                                  const float2* __restrict__ inc,
                                                  unsigned short* __restrict__ scaled) {
    int tid = blockIdx.x * 256 + threadIdx.x;
    int rc = tid & (RC - 1);
    int chunk = tid >> 10;
    int r = rc >> 5, c = rc & 31;
    float e = expf(-fabsf(a[r]));
    float gr = e * cosf(b[c]);
    float gi = e * sinf(b[c]);
    float2 s = inc[chunk * RC + rc];
    float sr = s.x, si = s.y;
    int t0 = chunk * CHUNK;
    for (int j = 0; j < CHUNK; ++j) {
        int t = t0 + j;
        float pre = fabsf(tc[t * 64 + r] * tc[t * 64 + 32 + c]) * invd[t];
        if (start[t]) {
            sr = pre; si = 0.f;
        } else {
            float nsr = pre + gr * sr - gi * si;
            float nsi =       gr * si + gi * sr;
            sr = nsr; si = nsi;
        }
        float m = sqrtf(sr * sr + si * si);
        float mag = log1pf(m);
        float f = (m > 0.f) ? (mag / m) : 0.f;
        scaled[(size_t)t * 2048 + rc]        = f2bf(si * f);
        scaled[(size_t)t * 2048 + 1024 + rc] = f2bf(sr * f);
    }
}

// ---------------------------------------------------------------------------
// C[4096,N] = A[4096,K]bf16 @ B[N,K]bf16^T (+bias), fp32 out.
// Tile 128x64, BK=32, 4 waves (each 64x32 = 4x2 frags of 16x16x32 MFMA).
// Reg-staged LDS with XOR slot swizzle (slot ^= (row>>1)&3) on write AND read.
template <int K, int N>
__global__ __launch_bounds__(256) void gemm_bt_mfma(const unsigned short* __restrict__ A,
                                                    const unsigned short* __restrict__ B,
                                                    const float* __restrict__ bias,
                                                    float* __restrict__ Cm) {
    __shared__ unsigned short As[128 * 32];
    __shared__ unsigned short Bs[64 * 32];
    const int tid = threadIdx.x;
    const int w = tid >> 6, lane = tid & 63;
    const int bm = blockIdx.y * 128, bn = blockIdx.x * 64;
    const int wr = w >> 1, wc = w & 1;            // wave tile: rows wr*64, cols wc*32
    const int lr = lane >> 2;                     // 0..15 staging row in group
    const int sl = lane & 3;                      // 16B slot
    const int swz_st = sl ^ ((lr >> 1) & 3);      // LDS write slot
    const size_t a_row0 = (size_t)(bm + w * 16 + lr);
    const size_t a_row1 = (size_t)(bm + 64 + w * 16 + lr);
    const size_t b_row  = (size_t)(bn + w * 16 + lr);
    const unsigned short* gA0 = A + a_row0 * K + sl * 8;
    const unsigned short* gA1 = A + a_row1 * K + sl * 8;
    const unsigned short* gB  = B + b_row  * K + sl * 8;
    const int wA0 = (w * 16 + lr) * 32 + swz_st * 8;
    const int wA1 = (64 + w * 16 + lr) * 32 + swz_st * 8;
    const int wB  = (w * 16 + lr) * 32 + swz_st * 8;
    const int fr = lane & 15;
    const int kslot = (lane >> 4) ^ ((fr >> 1) & 3);
    f32x4 acc[4][2] = {};

    uint4 va0 = *(const uint4*)gA0;
    uint4 va1 = *(const uint4*)gA1;
    uint4 vb  = *(const uint4*)gB;
    for (int k0 = 0; k0 < K; k0 += 32) {
        __syncthreads();
        *(uint4*)&As[wA0] = va0;
        *(uint4*)&As[wA1] = va1;
        *(uint4*)&Bs[wB]  = vb;
        __syncthreads();
        if (k0 + 32 < K) {
            va0 = *(const uint4*)(gA0 + k0 + 32);
            va1 = *(const uint4*)(gA1 + k0 + 32);
            vb  = *(const uint4*)(gB  + k0 + 32);
        }
        bf16x8 af[4], bfr[2];
#pragma unroll
        for (int mi = 0; mi < 4; ++mi) {
            int row = wr * 64 + mi * 16 + fr;
            af[mi] = *(const bf16x8*)&As[row * 32 + kslot * 8];
        }
#pragma unroll
        for (int ni = 0; ni < 2; ++ni) {
            int row = wc * 32 + ni * 16 + fr;
            bfr[ni] = *(const bf16x8*)&Bs[row * 32 + kslot * 8];
        }
#pragma unroll
        for (int mi = 0; mi < 4; ++mi)
#pragma unroll
            for (int ni = 0; ni < 2; ++ni)
                acc[mi][ni] = __builtin_amdgcn_mfma_f32_16x16x32_bf16(
                    af[mi], bfr[ni], acc[mi][ni], 0, 0, 0);
    }
    // epilogue: C/D layout col=lane&15, row=(lane>>4)*4+reg  [m89]
    const int ccol0 = bn + wc * 32 + fr;
    const int crow0 = bm + wr * 64 + (lane >> 4) * 4;
#pragma unroll
    for (int ni = 0; ni < 2; ++ni) {
        int col = ccol0 + ni * 16;
        float bv = bias ? bias[col] : 0.f;
#pragma unroll
        for (int mi = 0; mi < 4; ++mi)
#pragma unroll
            for (int q = 0; q < 4; ++q)
                Cm[(size_t)(crow0 + mi * 16 + q) * N + col] = acc[mi][ni][q] + bv;
    }
}

// ---------------------------------------------------------------------------
// Per-row LayerNorm + LeakyReLU.
//   zb   : optional bf16 z output (feeds next GEMM)
//   res  : optional fp32 residual input (x); hbf = f2bf(res + z)
//   hbf  : optional bf16 h output (next layer's proj input)
//   fout : optional fp32 final output
__global__ __launch_bounds__(256) void ln_lrelu_kernel(const float* __restrict__ y,
                                                       const float* __restrict__ g,
                                                       const float* __restrict__ be,
                                                       unsigned short* __restrict__ zb,
                                                       const float* __restrict__ res,
                                                       unsigned short* __restrict__ hbf,
                                                       float* __restrict__ fout) {
    int t = blockIdx.x;
    int tid = threadIdx.x;
    size_t base = (size_t)t * 512;
    float v0 = y[base + tid];
    float v1 = y[base + 256 + tid];
    float s = v0 + v1, ss = v0 * v0 + v1 * v1;
#pragma unroll
    for (int o = 32; o > 0; o >>= 1) {
        s  += __shfl_down(s, o);
        ss += __shfl_down(ss, o);
    }
    __shared__ float sh[8];
    __shared__ float mrs[2];
    int wid = tid >> 6, lane = tid & 63;
    if (lane == 0) { sh[wid] = s; sh[4 + wid] = ss; }
    __syncthreads();
    if (tid == 0) {
        float S = sh[0] + sh[1] + sh[2] + sh[3];
        float SS = sh[4] + sh[5] + sh[6] + sh[7];
        float m = S * (1.f / 512.f);
        float var = SS * (1.f / 512.f) - m * m;
        mrs[0] = m;
        mrs[1] = rsqrtf(var + LN_EPS);
    }
    __syncthreads();
    float m = mrs[0], rs = mrs[1];
    float z0 = g[tid] * (v0 - m) * rs + be[tid];
    float z1 = g[256 + tid] * (v1 - m) * rs + be[256 + tid];
    z0 = (z0 > 0.f) ? z0 : NEG_SLOPE * z0;
    z1 = (z1 > 0.f) ? z1 : NEG_SLOPE * z1;
    if (zb)   { zb[base + tid] = f2bf(z0); zb[base + 256 + tid] = f2bf(z1); }
    if (hbf) {
        float h0 = (res ? res[base + tid] : 0.f) + z0;
        float h1 = (res ? res[base + 256 + tid] : 0.f) + z1;
        hbf[base + tid] = f2bf(h0);
        hbf[base + 256 + tid] = f2bf(h1);
    }
    if (fout) { fout[base + tid] = z0; fout[base + 256 + tid] = z1; }
}

// ---------------------------------------------------------------------------
extern "C" void kernel_launch(void* const* d_in, const int* in_sizes, int n_in,
                              void* d_out, int out_size, void* d_ws, size_t ws_size,
                              hipStream_t stream) {
    const float* x     = (const float*)d_in[0];
    const int*   start = (const int*)d_in[1];
    const float* s0r = (const float*)d_in[3];
    const float* s0i = (const float*)d_in[4];
    const float* Wt  = (const float*)d_in[5];
    const float* Wc  = (const float*)d_in[6];
    const float* a   = (const float*)d_in[7];
    const float* b   = (const float*)d_in[8];
    const float* W0  = (const float*)d_in[9];
    const float* b0  = (const float*)d_in[10];
    const float* g0  = (const float*)d_in[11];
    const float* be0 = (const float*)d_in[12];
    const float* W1  = (const float*)d_in[13];
    const float* b1  = (const float*)d_in[14];
    const float* g1  = (const float*)d_in[15];
    const float* be1 = (const float*)d_in[16];
    float* out = (float*)d_out;
    float* ws  = (float*)d_ws;

    // workspace layout (float-unit offsets, all 16B aligned)
    float* tc     = ws;                                   //   262,144 f
    float* invd   = tc + 262144;                          //     4,096 f
    float4* ab4   = (float4*)(invd + 4096);               //   524,288 f
    float2* inc   = (float2*)(invd + 4096 + 524288);      //   262,144 f
    unsigned short* scaled = (unsigned short*)(invd + 4096 + 524288 + 262144); // 4,194,304 f
    float* ybuf   = invd + 4096 + 524288 + 262144 + 4194304;   // 2,097,152 f
    float* p      = ybuf + 2097152;
    unsigned short* zbuf_bf = (unsigned short*)p;  p += 1048576;   // 2,097,152 bf16
    unsigned short* x_bf    = (unsigned short*)p;  p += 1048576;   // 2,097,152 bf16
    unsigned short* h_bf    = (unsigned short*)p;  p += 1048576;   // 2,097,152 bf16
    unsigned short* Wtcbf   = (unsigned short*)p;  p += 32768;     //    65,536 bf16
    unsigned short* W0bf    = (unsigned short*)p;  p += 1048576;   // 2,097,152 bf16
    unsigned short* W1bf    = (unsigned short*)p;  p += 262144;    //   524,288 bf16
    // total ≈ 11.8M floats ≈ 47 MB

    // input/weight conversions
    f32_to_bf16_kernel<<<2048, 256, 0, stream>>>((const float4*)x, (ushort4*)x_bf,
                                                 TT * DD / 4);
    f32_to_bf16_kernel<<<2048, 256, 0, stream>>>((const float4*)W0, (ushort4*)W0bf,
                                                 LL * DD * 2048 / 4);
    f32_to_bf16_kernel<<<512, 256, 0, stream>>>((const float4*)W1, (ushort4*)W1bf,
                                                LL * DD * DD / 4);
    pack_wtc_kernel<<<64, 256, 0, stream>>>(Wt, Wc, (ushort4*)Wtcbf);

    for (int i = 0; i < LL; ++i) {
        const unsigned short* hb = (i == 0) ? x_bf : h_bf;
        // proj: tc[4096,64] = h @ [Wt;Wc]^T
        gemm_bt_mfma<512, 64><<<dim3(1, 32), 256, 0, stream>>>(
            hb, Wtcbf + (size_t)i * 64 * 512, nullptr, tc);
        denom_kernel<<<16, 256, 0, stream>>>(tc, invd);
        scan_pass1<<<NCHUNK * RC / 256, 256, 0, stream>>>(
            tc, invd, start, a + i * RR, b + i * CC, ab4);
        scan_combine<<<4, 256, 0, stream>>>(ab4, s0r + i * RC, s0i + i * RC, inc);
        scan_pass2<<<NCHUNK * RC / 256, 256, 0, stream>>>(
            tc, invd, start, a + i * RR, b + i * CC, inc, scaled);
        gemm_bt_mfma<2048, 512><<<dim3(8, 32), 256, 0, stream>>>(
            scaled, W0bf + (size_t)i * DD * 2048, b0 + i * DD, ybuf);
        ln_lrelu_kernel<<<TT, 256, 0, stream>>>(
            ybuf, g0 + i * DD, be0 + i * DD, zbuf_bf, nullptr, nullptr, nullptr);
        gemm_bt_mfma<512, 512><<<dim3(8, 32), 256, 0, stream>>>(
            zbuf_bf, W1bf + (size_t)i * DD * DD, b1 + i * DD, ybuf);
        ln_lrelu_kernel<<<TT, 256, 0, stream>>>(
            ybuf, g1 + i * DD, be1 + i * DD, nullptr,
            (i < LL - 1) ? x : nullptr,
            (i < LL - 1) ? h_bf : nullptr,
            (i == LL - 1) ? out : nullptr);
    }
}

// Round 4
// 214.829 us; speedup vs baseline: 3.2691x; 1.0750x over previous
//
#include <hip/hip_runtime.h>
#include <math.h>

// Problem constants
#define TT 4096
#define DD 512
#define RR 32
#define CC 32
#define RC 1024
#define LL 2
#define CHUNK 32
#define NCHUNK 128
#define NEG_SLOPE 0.01f
#define LN_EPS 1e-5f

typedef __attribute__((ext_vector_type(8))) __bf16 bf16x8;
typedef __attribute__((ext_vector_type(4))) float f32x4;

__device__ __forceinline__ unsigned short f2bf(float f) {
    unsigned int u = __builtin_bit_cast(unsigned int, f);
    u += 0x7fffu + ((u >> 16) & 1u);   // round-to-nearest-even
    return (unsigned short)(u >> 16);
}

// ---------------------------------------------------------------------------
// Fused f32 -> bf16 conversion for x, W0, W1 (one launch).
#define NX4  524288   // 4096*512/4
#define NW04 524288   // 2*512*2048/4
#define NW14 131072   // 2*512*512/4
__global__ __launch_bounds__(256) void conv_all_kernel(const float4* __restrict__ x,
                                                       const float4* __restrict__ W0,
                                                       const float4* __restrict__ W1,
                                                       ushort4* __restrict__ xb,
                                                       ushort4* __restrict__ W0b,
                                                       ushort4* __restrict__ W1b) {
    int i = blockIdx.x * 256 + threadIdx.x;   // < NX4+NW04+NW14
    const float4* src; ushort4* dst; int j;
    if (i < NX4) { src = x; dst = xb; j = i; }
    else if (i < NX4 + NW04) { src = W0; dst = W0b; j = i - NX4; }
    else { src = W1; dst = W1b; j = i - NX4 - NW04; }
    float4 v = src[j];
    ushort4 o;
    o.x = f2bf(v.x); o.y = f2bf(v.y); o.z = f2bf(v.z); o.w = f2bf(v.w);
    dst[j] = o;
}

// ---------------------------------------------------------------------------
// Pack Wt[L,32,512] and Wc[L,32,512] into Wtc[L,64,512] bf16 (rows 0..31 = Wt)
__global__ __launch_bounds__(256) void pack_wtc_kernel(const float* __restrict__ Wt,
                                                       const float* __restrict__ Wc,
                                                       ushort4* __restrict__ Wtc) {
    int i = blockIdx.x * 256 + threadIdx.x;      // L*64*512/4 total
    int e = i * 4;
    int l = e >> 15;
    int r = (e >> 9) & 63;
    int k = e & 511;
    const float4 v = (r < 32)
        ? *(const float4*)&Wt[((size_t)l * 32 + r) * 512 + k]
        : *(const float4*)&Wc[((size_t)l * 32 + (r - 32)) * 512 + k];
    ushort4 o;
    o.x = f2bf(v.x); o.y = f2bf(v.y); o.z = f2bf(v.z); o.w = f2bf(v.w);
    Wtc[i] = o;
}

// ---------------------------------------------------------------------------
// Reduce 4 split-K partials of proj, compute |.|, fold invd into tr half:
//   tcabs[t, r]    = |tr_r| * invd      (r < 32)
//   tcabs[t, 32+c] = |ct_c|
// grid 128 blocks x 256 thr; block handles 32 rows, 8 threads/row x 8 elems.
__global__ __launch_bounds__(256) void denom_reduce_kernel(const float* __restrict__ tcp,
                                                           float* __restrict__ tcabs) {
    int lrow = threadIdx.x >> 3;            // 0..31
    int q = threadIdx.x & 7;                // 0..7
    int row = blockIdx.x * 32 + lrow;
    size_t base = (size_t)row * 64 + q * 8;
    float v[8];
#pragma unroll
    for (int e = 0; e < 8; ++e) v[e] = 0.f;
#pragma unroll
    for (int z = 0; z < 4; ++z) {
        const float4* p = (const float4*)(tcp + (size_t)z * TT * 64 + base);
        float4 u0 = p[0], u1 = p[1];
        v[0] += u0.x; v[1] += u0.y; v[2] += u0.z; v[3] += u0.w;
        v[4] += u1.x; v[5] += u1.y; v[6] += u1.z; v[7] += u1.w;
    }
    float s = 0.f;
#pragma unroll
    for (int e = 0; e < 8; ++e) { v[e] = fabsf(v[e]); s += v[e]; }
    __shared__ float red[32][8];
    red[lrow][q] = s;
    __syncthreads();
    float str = red[lrow][0] + red[lrow][1] + red[lrow][2] + red[lrow][3];
    float stc = red[lrow][4] + red[lrow][5] + red[lrow][6] + red[lrow][7];
    float inv = 1.f / (1e-8f + str * stc);
    float scale = (q < 4) ? inv : 1.f;
    float4 o0 = make_float4(v[0] * scale, v[1] * scale, v[2] * scale, v[3] * scale);
    float4 o1 = make_float4(v[4] * scale, v[5] * scale, v[6] * scale, v[7] * scale);
    float4* dst = (float4*)(tcabs + base);
    dst[0] = o0; dst[1] = o1;
}

// ---------------------------------------------------------------------------
// Scan pass 1: per (chunk, r, c) affine transform (alpha, beta) with resets.
__global__ __launch_bounds__(256) void scan_pass1(const float* __restrict__ tcabs,
                                                  const int* __restrict__ start,
                                                  const float* __restrict__ a,
                                                  const float* __restrict__ b,
                                                  float4* __restrict__ ab4) {
    int tid = blockIdx.x * 256 + threadIdx.x;   // NCHUNK*RC = 131072
    int rc = tid & (RC - 1);
    int chunk = tid >> 10;
    int r = rc >> 5, c = rc & 31;
    float e = expf(-fabsf(a[r]));
    float gr = e * cosf(b[c]);
    float gi = e * sinf(b[c]);
    float alr = 1.f, ali = 0.f, ber = 0.f, bei = 0.f;
    int t0 = chunk * CHUNK;
    for (int j = 0; j < CHUNK; ++j) {
        int t = t0 + j;
        float pre = tcabs[t * 64 + r] * tcabs[t * 64 + 32 + c];
        if (start[t]) {
            alr = 0.f; ali = 0.f; ber = pre; bei = 0.f;
        } else {
            float nbr = pre + gr * ber - gi * bei;
            float nbi =       gr * bei + gi * ber;
            float nar = gr * alr - gi * ali;
            float nai = gr * ali + gi * alr;
            ber = nbr; bei = nbi; alr = nar; ali = nai;
        }
    }
    ab4[chunk * RC + rc] = make_float4(alr, ali, ber, bei);
}

// ---------------------------------------------------------------------------
// Combine: sequential scan over NCHUNK chunk transforms per (r,c),
// 8-deep batched prefetch.
__global__ __launch_bounds__(256) void scan_combine(const float4* __restrict__ ab4,
                                                    const float* __restrict__ s0r,
                                                    const float* __restrict__ s0i,
                                                    float2* __restrict__ inc) {
    int rc = blockIdx.x * 256 + threadIdx.x;   // 1024 total
    float sr = s0r[rc], si = s0i[rc];
    for (int kb = 0; kb < NCHUNK; kb += 8) {
        float4 buf[8];
#pragma unroll
        for (int u = 0; u < 8; ++u) buf[u] = ab4[(kb + u) * RC + rc];
#pragma unroll
        for (int u = 0; u < 8; ++u) {
            inc[(kb + u) * RC + rc] = make_float2(sr, si);
            float nsr = buf[u].z + buf[u].x * sr - buf[u].y * si;
            float nsi = buf[u].w + buf[u].x * si + buf[u].y * sr;
            sr = nsr; si = nsi;
        }
    }
}

// ---------------------------------------------------------------------------
// Scan pass 2: rescan chunk from incoming state, emit scaled features (bf16).
__global__ __launch_bounds__(256) void scan_pass2(const float* __restrict__ tcabs,
                                                  const int* __restrict__ start,
                                                  const float* __restrict__ a,
                                                  const float* __restrict__ b,
                                                  const float2* __restrict__ inc,
                                                  unsigned short* __restrict__ scaled) {
    int tid = blockIdx.x * 256 + threadIdx.x;
    int rc = tid & (RC - 1);
    int chunk = tid >> 10;
    int r = rc >> 5, c = rc & 31;
    float e = expf(-fabsf(a[r]));
    float gr = e * cosf(b[c]);
    float gi = e * sinf(b[c]);
    float2 s = inc[chunk * RC + rc];
    float sr = s.x, si = s.y;
    int t0 = chunk * CHUNK;
    for (int j = 0; j < CHUNK; ++j) {
        int t = t0 + j;
        float pre = tcabs[t * 64 + r] * tcabs[t * 64 + 32 + c];
        if (start[t]) {
            sr = pre; si = 0.f;
        } else {
            float nsr = pre + gr * sr - gi * si;
            float nsi =       gr * si + gi * sr;
            sr = nsr; si = nsi;
        }
        float m = sqrtf(sr * sr + si * si);
        float mag = log1pf(m);
        float f = (m > 0.f) ? (mag / m) : 0.f;
        scaled[(size_t)t * 2048 + rc]        = f2bf(si * f);
        scaled[(size_t)t * 2048 + 1024 + rc] = f2bf(sr * f);
    }
}

// ---------------------------------------------------------------------------
// Cm_partial[z][4096,N] = A[4096, Kz]bf16 @ B[N, Kz]bf16^T  (split-K partials)
// Tile 128x64, BK=32, 4 waves (each 64x32 = 4x2 frags of 16x16x32 MFMA).
// Reg-staged LDS with XOR slot swizzle on write AND read.
template <int K, int N, int SPLITK>
__global__ __launch_bounds__(256) void gemm_bt_mfma(const unsigned short* __restrict__ A,
                                                    const unsigned short* __restrict__ B,
                                                    float* __restrict__ Cm) {
    __shared__ unsigned short As[128 * 32];
    __shared__ unsigned short Bs[64 * 32];
    const int tid = threadIdx.x;
    const int w = tid >> 6, lane = tid & 63;
    const int bm = blockIdx.y * 128, bn = blockIdx.x * 64;
    const int kbeg = blockIdx.z * (K / SPLITK);
    const int kend = kbeg + (K / SPLITK);
    const int wr = w >> 1, wc = w & 1;
    const int lr = lane >> 2;
    const int sl = lane & 3;
    const int swz_st = sl ^ ((lr >> 1) & 3);
    const size_t a_row0 = (size_t)(bm + w * 16 + lr);
    const size_t a_row1 = (size_t)(bm + 64 + w * 16 + lr);
    const size_t b_row  = (size_t)(bn + w * 16 + lr);
    const unsigned short* gA0 = A + a_row0 * K + sl * 8;
    const unsigned short* gA1 = A + a_row1 * K + sl * 8;
    const unsigned short* gB  = B + b_row  * K + sl * 8;
    const int wA0 = (w * 16 + lr) * 32 + swz_st * 8;
    const int wA1 = (64 + w * 16 + lr) * 32 + swz_st * 8;
    const int wB  = (w * 16 + lr) * 32 + swz_st * 8;
    const int fr = lane & 15;
    const int kslot = (lane >> 4) ^ ((fr >> 1) & 3);
    f32x4 acc[4][2] = {};

    uint4 va0 = *(const uint4*)(gA0 + kbeg);
    uint4 va1 = *(const uint4*)(gA1 + kbeg);
    uint4 vb  = *(const uint4*)(gB  + kbeg);
    for (int k0 = kbeg; k0 < kend; k0 += 32) {
        __syncthreads();
        *(uint4*)&As[wA0] = va0;
        *(uint4*)&As[wA1] = va1;
        *(uint4*)&Bs[wB]  = vb;
        __syncthreads();
        if (k0 + 32 < kend) {
            va0 = *(const uint4*)(gA0 + k0 + 32);
            va1 = *(const uint4*)(gA1 + k0 + 32);
            vb  = *(const uint4*)(gB  + k0 + 32);
        }
        bf16x8 af[4], bfr[2];
#pragma unroll
        for (int mi = 0; mi < 4; ++mi) {
            int row = wr * 64 + mi * 16 + fr;
            af[mi] = *(const bf16x8*)&As[row * 32 + kslot * 8];
        }
#pragma unroll
        for (int ni = 0; ni < 2; ++ni) {
            int row = wc * 32 + ni * 16 + fr;
            bfr[ni] = *(const bf16x8*)&Bs[row * 32 + kslot * 8];
        }
#pragma unroll
        for (int mi = 0; mi < 4; ++mi)
#pragma unroll
            for (int ni = 0; ni < 2; ++ni)
                acc[mi][ni] = __builtin_amdgcn_mfma_f32_16x16x32_bf16(
                    af[mi], bfr[ni], acc[mi][ni], 0, 0, 0);
    }
    // epilogue: C/D layout col=lane&15, row=(lane>>4)*4+reg  [m89]
    float* Cz = Cm + (size_t)blockIdx.z * TT * N;
    const int ccol0 = bn + wc * 32 + fr;
    const int crow0 = bm + wr * 64 + (lane >> 4) * 4;
#pragma unroll
    for (int ni = 0; ni < 2; ++ni) {
        int col = ccol0 + ni * 16;
#pragma unroll
        for (int mi = 0; mi < 4; ++mi)
#pragma unroll
            for (int q = 0; q < 4; ++q)
                Cz[(size_t)(crow0 + mi * 16 + q) * N + col] = acc[mi][ni][q];
    }
}

// ---------------------------------------------------------------------------
// Per-row: y = y0 + y1 + bias; LayerNorm + LeakyReLU.
//   zb   : optional bf16 z output (feeds next GEMM)
//   res  : optional fp32 residual input (x); hbf = f2bf(res + z)
//   hbf  : optional bf16 h output (next layer's proj input)
//   fout : optional fp32 final output
__global__ __launch_bounds__(256) void ln_lrelu_kernel(const float* __restrict__ y0,
                                                       const float* __restrict__ y1,
                                                       const float* __restrict__ badd,
                                                       const float* __restrict__ g,
                                                       const float* __restrict__ be,
                                                       unsigned short* __restrict__ zb,
                                                       const float* __restrict__ res,
                                                       unsigned short* __restrict__ hbf,
                                                       float* __restrict__ fout) {
    int t = blockIdx.x;
    int tid = threadIdx.x;
    size_t base = (size_t)t * 512;
    float v0 = y0[base + tid] + y1[base + tid] + badd[tid];
    float v1 = y0[base + 256 + tid] + y1[base + 256 + tid] + badd[256 + tid];
    float s = v0 + v1, ss = v0 * v0 + v1 * v1;
#pragma unroll
    for (int o = 32; o > 0; o >>= 1) {
        s  += __shfl_down(s, o);
        ss += __shfl_down(ss, o);
    }
    __shared__ float sh[8];
    __shared__ float mrs[2];
    int wid = tid >> 6, lane = tid & 63;
    if (lane == 0) { sh[wid] = s; sh[4 + wid] = ss; }
    __syncthreads();
    if (tid == 0) {
        float S = sh[0] + sh[1] + sh[2] + sh[3];
        float SS = sh[4] + sh[5] + sh[6] + sh[7];
        float m = S * (1.f / 512.f);
        float var = SS * (1.f / 512.f) - m * m;
        mrs[0] = m;
        mrs[1] = rsqrtf(var + LN_EPS);
    }
    __syncthreads();
    float m = mrs[0], rs = mrs[1];
    float z0 = g[tid] * (v0 - m) * rs + be[tid];
    float z1 = g[256 + tid] * (v1 - m) * rs + be[256 + tid];
    z0 = (z0 > 0.f) ? z0 : NEG_SLOPE * z0;
    z1 = (z1 > 0.f) ? z1 : NEG_SLOPE * z1;
    if (zb)   { zb[base + tid] = f2bf(z0); zb[base + 256 + tid] = f2bf(z1); }
    if (hbf) {
        float h0 = (res ? res[base + tid] : 0.f) + z0;
        float h1 = (res ? res[base + 256 + tid] : 0.f) + z1;
        hbf[base + tid] = f2bf(h0);
        hbf[base + 256 + tid] = f2bf(h1);
    }
    if (fout) { fout[base + tid] = z0; fout[base + 256 + tid] = z1; }
}

// ---------------------------------------------------------------------------
extern "C" void kernel_launch(void* const* d_in, const int* in_sizes, int n_in,
                              void* d_out, int out_size, void* d_ws, size_t ws_size,
                              hipStream_t stream) {
    const float* x     = (const float*)d_in[0];
    const int*   start = (const int*)d_in[1];
    const float* s0r = (const float*)d_in[3];
    const float* s0i = (const float*)d_in[4];
    const float* Wt  = (const float*)d_in[5];
    const float* Wc  = (const float*)d_in[6];
    const float* a   = (const float*)d_in[7];
    const float* b   = (const float*)d_in[8];
    const float* W0  = (const float*)d_in[9];
    const float* b0  = (const float*)d_in[10];
    const float* g0  = (const float*)d_in[11];
    const float* be0 = (const float*)d_in[12];
    const float* W1  = (const float*)d_in[13];
    const float* b1  = (const float*)d_in[14];
    const float* g1  = (const float*)d_in[15];
    const float* be1 = (const float*)d_in[16];
    float* out = (float*)d_out;
    float* ws  = (float*)d_ws;

    // workspace layout (float-unit offsets, all 16B aligned)  ~59.9 MB
    float* p = ws;
    float* tcp    = p; p += 1048576;                 // [4][4096][64] f32 partials
    float* tcabs  = p; p += 262144;                  // [4096][64] f32 (invd folded)
    float4* ab4   = (float4*)p; p += 524288;         // [128][1024] float4
    float2* inc   = (float2*)p; p += 262144;         // [128][1024] float2
    unsigned short* scaled = (unsigned short*)p; p += 4194304;   // [4096][2048] bf16
    float* ybufp  = p; p += 4194304;                 // [2][4096][512] f32 partials
    unsigned short* zbuf_bf = (unsigned short*)p; p += 1048576;  // [4096][512] bf16
    unsigned short* x_bf    = (unsigned short*)p; p += 1048576;
    unsigned short* h_bf    = (unsigned short*)p; p += 1048576;
    unsigned short* Wtcbf   = (unsigned short*)p; p += 32768;    // [2][64][512] bf16
    unsigned short* W0bf    = (unsigned short*)p; p += 1048576;  // [2][512][2048] bf16
    unsigned short* W1bf    = (unsigned short*)p; p += 262144;   // [2][512][512] bf16

    conv_all_kernel<<<(NX4 + NW04 + NW14) / 256, 256, 0, stream>>>(
        (const float4*)x, (const float4*)W0, (const float4*)W1,
        (ushort4*)x_bf, (ushort4*)W0bf, (ushort4*)W1bf);
    pack_wtc_kernel<<<64, 256, 0, stream>>>(Wt, Wc, (ushort4*)Wtcbf);

    for (int i = 0; i < LL; ++i) {
        const unsigned short* hb = (i == 0) ? x_bf : h_bf;
        gemm_bt_mfma<512, 64, 4><<<dim3(1, 32, 4), 256, 0, stream>>>(
            hb, Wtcbf + (size_t)i * 64 * 512, tcp);
        denom_reduce_kernel<<<128, 256, 0, stream>>>(tcp, tcabs);
        scan_pass1<<<NCHUNK * RC / 256, 256, 0, stream>>>(
            tcabs, start, a + i * RR, b + i * CC, ab4);
        scan_combine<<<4, 256, 0, stream>>>(ab4, s0r + i * RC, s0i + i * RC, inc);
        scan_pass2<<<NCHUNK * RC / 256, 256, 0, stream>>>(
            tcabs, start, a + i * RR, b + i * CC, inc, scaled);
        gemm_bt_mfma<2048, 512, 2><<<dim3(8, 32, 2), 256, 0, stream>>>(
            scaled, W0bf + (size_t)i * 512 * 2048, ybufp);
        ln_lrelu_kernel<<<TT, 256, 0, stream>>>(
            ybufp, ybufp + (size_t)TT * 512, b0 + i * DD, g0 + i * DD, be0 + i * DD,
            zbuf_bf, nullptr, nullptr, nullptr);
        gemm_bt_mfma<512, 512, 2><<<dim3(8, 32, 2), 256, 0, stream>>>(
            zbuf_bf, W1bf + (size_t)i * 512 * 512, ybufp);
        ln_lrelu_kernel<<<TT, 256, 0, stream>>>(
            ybufp, ybufp + (size_t)TT * 512, b1 + i * DD, g1 + i * DD, be1 + i * DD,
            nullptr,
            (i < LL - 1) ? x : nullptr,
            (i < LL - 1) ? h_bf : nullptr,
            (i == LL - 1) ? out : nullptr);
    }
}